// Round 4
// baseline (141.433 us; speedup 1.0000x reference)
//
#include <hip/hip_runtime.h>

// log1p thresholds (fp32): ln(6), ln(26), ln(51)
#define THR1 1.7917594909667969f
#define THR2 3.2580966949462891f
#define THR3 3.9318256378173828f
#define W1 0.2f
#define W2 30.0f
#define W3 2500.0f
#define W4 20000.0f

#define BLOCK 256
#define UNROLL 8                   // float4-pairs per thread: 16 x 16B loads in flight
#define GRID 1920                  // 1920*256*8 = 3,932,160 = n/4 exactly (single-shot)

__device__ __forceinline__ float bucket_w(float y) {
    return (y < THR1) ? W1 : ((y < THR2) ? W2 : ((y < THR3) ? W3 : W4));
}

__device__ __forceinline__ void accum(float4 a, float4 b, float& num, float& den) {
    float w;
    w = bucket_w(b.x); num += w * fabsf(b.x - a.x); den += w;
    w = bucket_w(b.y); num += w * fabsf(b.y - a.y); den += w;
    w = bucket_w(b.z); num += w * fabsf(b.z - a.z); den += w;
    w = bucket_w(b.w); num += w * fabsf(b.w - a.w); den += w;
}

__global__ __launch_bounds__(BLOCK) void mae_stage1(
    const float* __restrict__ y_pred,
    const float* __restrict__ y_true,
    float2* __restrict__ partials,   // one (num,den) per block
    int n)
{
    const int n4 = n >> 2;
    const int CHUNK = BLOCK * UNROLL;        // 2048 float4s per block
    const int nchunks = n4 / CHUNK;          // == GRID for this problem
    const float4* __restrict__ p4 = (const float4*)y_pred;
    const float4* __restrict__ t4 = (const float4*)y_true;

    float num = 0.0f, den = 0.0f;

    // single-shot steady state: no bounds checks, 16 independent 16B loads
    for (int c = blockIdx.x; c < nchunks; c += GRID) {   // exactly 1 iter here
        const int base = c * CHUNK + threadIdx.x;
        float4 a[UNROLL], b[UNROLL];
        #pragma unroll
        for (int k = 0; k < UNROLL; ++k) a[k] = p4[base + k * BLOCK];
        #pragma unroll
        for (int k = 0; k < UNROLL; ++k) b[k] = t4[base + k * BLOCK];
        #pragma unroll
        for (int k = 0; k < UNROLL; ++k) accum(a[k], b[k], num, den);
    }

    // tail: elements beyond full chunks (zero for this problem shape)
    const int tail_start = nchunks * CHUNK * 4;   // element index
    for (int j = tail_start + blockIdx.x * BLOCK + threadIdx.x; j < n;
         j += GRID * BLOCK) {
        const float aa = y_pred[j];
        const float bb = y_true[j];
        const float w = bucket_w(bb);
        num += w * fabsf(bb - aa);
        den += w;
    }

    // 64-lane wave reduction
    #pragma unroll
    for (int off = 32; off > 0; off >>= 1) {
        num += __shfl_down(num, off, 64);
        den += __shfl_down(den, off, 64);
    }

    __shared__ float s_num[4];
    __shared__ float s_den[4];
    const int wave = threadIdx.x >> 6;
    const int lane = threadIdx.x & 63;
    if (lane == 0) { s_num[wave] = num; s_den[wave] = den; }
    __syncthreads();

    if (threadIdx.x == 0) {
        partials[blockIdx.x] = make_float2(s_num[0] + s_num[1] + s_num[2] + s_num[3],
                                           s_den[0] + s_den[1] + s_den[2] + s_den[3]);
    }
}

__global__ __launch_bounds__(BLOCK) void mae_stage2(
    const float2* __restrict__ partials, int nblocks, float* __restrict__ out)
{
    float num = 0.0f, den = 0.0f;
    for (int i = threadIdx.x; i < nblocks; i += BLOCK) {
        const float2 v = partials[i];
        num += v.x; den += v.y;
    }

    #pragma unroll
    for (int off = 32; off > 0; off >>= 1) {
        num += __shfl_down(num, off, 64);
        den += __shfl_down(den, off, 64);
    }

    __shared__ float s_num[4];
    __shared__ float s_den[4];
    const int wave = threadIdx.x >> 6;
    const int lane = threadIdx.x & 63;
    if (lane == 0) { s_num[wave] = num; s_den[wave] = den; }
    __syncthreads();

    if (threadIdx.x == 0) {
        const float bn = s_num[0] + s_num[1] + s_num[2] + s_num[3];
        const float bd = s_den[0] + s_den[1] + s_den[2] + s_den[3];
        out[0] = bn / bd;
    }
}

extern "C" void kernel_launch(void* const* d_in, const int* in_sizes, int n_in,
                              void* d_out, int out_size, void* d_ws, size_t ws_size,
                              hipStream_t stream)
{
    const float* y_pred = (const float*)d_in[0];
    const float* y_true = (const float*)d_in[1];
    float* out = (float*)d_out;
    float2* partials = (float2*)d_ws;       // GRID float2s, fully overwritten each call
    const int n = in_sizes[0];

    mae_stage1<<<GRID, BLOCK, 0, stream>>>(y_pred, y_true, partials, n);
    mae_stage2<<<1, BLOCK, 0, stream>>>(partials, GRID, out);
}